// Round 9
// baseline (126.915 us; speedup 1.0000x reference)
//
#include <hip/hip_runtime.h>
#include <stdint.h>

typedef __attribute__((ext_vector_type(8))) short short8;
typedef __attribute__((ext_vector_type(4))) short short4v;
typedef __attribute__((ext_vector_type(4))) float float4v;
typedef __attribute__((ext_vector_type(16))) float float16v;
typedef __attribute__((ext_vector_type(4))) uint32_t uint4v;

__device__ __forceinline__ short f2bf(float f) {
    union { float f; uint32_t u; } v; v.f = f;
    uint32_t u = v.u;
    uint32_t r = (u + 0x7fffu + ((u >> 16) & 1u)) >> 16;
    return (short)r;
}

#if __has_builtin(__builtin_amdgcn_cvt_pk_bf16_f32)
typedef __bf16 bf16x2_t __attribute__((ext_vector_type(2)));
__device__ __forceinline__ uint32_t cvt_pk2(float a, float b) {
    union { bf16x2_t v; uint32_t u; } c;
    c.v = __builtin_amdgcn_cvt_pk_bf16_f32(a, b);
    return c.u;
}
#else
__device__ __forceinline__ uint32_t cvt_pk2(float a, float b) {
    union { float f; uint32_t u; } x, y; x.f = a; y.f = b;
    return ((x.u + 0x8000u) >> 16) | ((y.u + 0x8000u) & 0xFFFF0000u);
}
#endif

// ---------------- coalesced weight transpose-convert (r16) ----------------

__global__ __launch_bounds__(256) void cvtW_kernel(const float* __restrict__ wqkv,
                                                   const float* __restrict__ wproj,
                                                   short* __restrict__ outq,
                                                   short* __restrict__ outp) {
    __shared__ short T[64][66];
    int t = blockIdx.x;
    const float* src; short* dst; int srcld, k0, n0;
    if (t < 48) {
        k0 = (t & 3) * 64; n0 = (t >> 2) * 64;
        src = wqkv; srcld = 768; dst = outq;
    } else {
        int i = t - 48;
        k0 = (i & 3) * 64; n0 = (i >> 2) * 64;
        src = wproj; srcld = 256; dst = outp;
    }
    int row = threadIdx.x >> 2, seg = threadIdx.x & 3;
    const float* s = src + (size_t)(k0 + row) * srcld + n0 + seg * 16;
    float4 f0 = *(const float4*)s;
    float4 f1 = *(const float4*)(s + 4);
    float4 f2 = *(const float4*)(s + 8);
    float4 f3 = *(const float4*)(s + 12);
    uint32_t* tw = (uint32_t*)&T[row][seg * 16];
    tw[0] = cvt_pk2(f0.x, f0.y); tw[1] = cvt_pk2(f0.z, f0.w);
    tw[2] = cvt_pk2(f1.x, f1.y); tw[3] = cvt_pk2(f1.z, f1.w);
    tw[4] = cvt_pk2(f2.x, f2.y); tw[5] = cvt_pk2(f2.z, f2.w);
    tw[6] = cvt_pk2(f3.x, f3.y); tw[7] = cvt_pk2(f3.z, f3.w);
    __syncthreads();
    short tmp[16] __attribute__((aligned(16)));
    #pragma unroll
    for (int j = 0; j < 16; ++j) tmp[j] = T[seg * 16 + j][row];
    short* d = dst + (size_t)(n0 + row) * 256 + k0 + seg * 16;
    *(short8*)d       = *(short8*)&tmp[0];
    *(short8*)(d + 8) = *(short8*)&tmp[8];
}

// ---------------- GEMM (r5 structure — best measured): 64x64 tile ----------------
// Three GEMM variants measured (r5 / gemm2+xb / gemm2): non-attn block is
// insensitive within ±3us at this K=256 shape.  Frozen on r5.

template<int MODE>
__global__ __launch_bounds__(256) void gemm_kernel(
    const void* __restrict__ Ap, const short* __restrict__ Bt,
    const float* __restrict__ bias,
    short* __restrict__ outQ, short* __restrict__ outK, short* __restrict__ outV,
    float* __restrict__ outP)
{
    const int K = 256;
    int m0 = blockIdx.x * 64;
    int n0 = blockIdx.y * 64;
    int tid = threadIdx.x;
    int wave = tid >> 6, lane = tid & 63, quad = lane >> 4, lc = lane & 15;

    __shared__ __align__(16) short As[64 * 48];
    __shared__ __align__(16) short Bs[64 * 48];

    float4v acc[4];
    #pragma unroll
    for (int t = 0; t < 4; ++t) acc[t] = (float4v){0.f, 0.f, 0.f, 0.f};

    int srow = tid >> 2, sseg = tid & 3;

    for (int c = 0; c < K; c += 32) {
        __syncthreads();
        if (MODE == 0) {
            const float* src = (const float*)Ap + (size_t)(m0 + srow) * K + c + sseg * 8;
            float4 f0 = *(const float4*)src;
            float4 f1 = *(const float4*)(src + 4);
            uint4v u; u.x = cvt_pk2(f0.x, f0.y); u.y = cvt_pk2(f0.z, f0.w);
            u.z = cvt_pk2(f1.x, f1.y); u.w = cvt_pk2(f1.z, f1.w);
            *(uint4v*)(&As[srow * 48 + sseg * 8]) = u;
        } else {
            *(short8*)(&As[srow * 48 + sseg * 8]) =
                *(const short8*)((const short*)Ap + (size_t)(m0 + srow) * K + c + sseg * 8);
        }
        *(short8*)(&Bs[srow * 48 + sseg * 8]) =
            *(const short8*)(Bt + (size_t)(n0 + srow) * K + c + sseg * 8);
        __syncthreads();

        short8 af = *(short8*)(&As[(wave * 16 + lc) * 48 + quad * 8]);
        #pragma unroll
        for (int t = 0; t < 4; ++t) {
            short8 bf = *(short8*)(&Bs[(t * 16 + lc) * 48 + quad * 8]);
            acc[t] = __builtin_amdgcn_mfma_f32_16x16x32_bf16(af, bf, acc[t], 0, 0, 0);
        }
    }

    #pragma unroll
    for (int t = 0; t < 4; ++t) {
        int cg = n0 + t * 16 + lc;
        float bv = bias[cg];
        #pragma unroll
        for (int r = 0; r < 4; ++r) {
            int rg = m0 + wave * 16 + quad * 4 + r;
            float val = acc[t][r] + bv;
            if (MODE == 0) {
                int sq = cg >> 8, rem = cg & 255, h = rem >> 4, d = rem & 15;
                int b = rg >> 11, n = rg & 2047;
                if (sq == 0) val *= 1.4426950408889634f;  // fold log2(e) into Q
                short* dst = (sq == 0) ? outQ : ((sq == 1) ? outK : outV);
                dst[((((size_t)b * 16 + h) * 2048 + n) << 4) + d] = f2bf(val);
            } else {
                outP[(size_t)rg * 256 + cg] = val;
            }
        }
    }
}

// ---------------- flash attention (r19 resubmit: 8-wave blocks) ------------------
// R8's bench never ran (container acquire failed twice — infra).  Kernel
// re-audited: barriers uniform, all indices in bounds, staging bijective,
// LDS 16.9 KB, launch_bounds(512,2) = 256-reg cap (7x headroom, no R1 squeeze).
// Hypothesis unchanged: block granularity is the residency lever.  R7 falsified
// the register model (VGPR 64->44->36, occupancy pinned ~27%); R1's 512-thread
// kernel measured 60% occupancy on the same grid ratio (its failure was spill,
// which r18's 36-VGPR main loop cannot reproduce under a 256-reg cap).
// Tripwires: WRITE_SIZE must stay 4096 KB; VGPR <= 48.
// Pre-committed null read: occupancy flat or dur >= 48us -> residency pinned by
// an invisible limiter; revert to r18 and declare the plateau.

__global__ __launch_bounds__(512, 2) void attn_kernel(
    const short* __restrict__ Q, const short* __restrict__ Kp, const short* __restrict__ V,
    short* __restrict__ Out)
{
    const int N = 2048;
    int bh = blockIdx.y;
    int b = bh >> 4, h = bh & 15;
    int tid = threadIdx.x;
    int wave = tid >> 6, lane = tid & 63;
    int m = lane & 31, hi = lane >> 5;
    int qbase = blockIdx.x * 256 + wave * 32;

    const short* Qh = Q + (size_t)bh * N * 16;
    const short* Kh = Kp + (size_t)bh * N * 16;
    const short* Vh = V + (size_t)bh * N * 16;

    __shared__ __align__(16) short Vt[32][264];

    for (int idx = tid; idx < 16 * 264; idx += 512) {
        int row = 16 + idx / 264;
        int col = idx - (row - 16) * 264;
        Vt[row][col] = (row == 16) ? (short)0x3F80 : (short)0;
    }

    short8 qf = *(const short8*)(Qh + (size_t)(qbase + m) * 16 + hi * 8);

    float16v Oacc;
    #pragma unroll
    for (int j = 0; j < 16; ++j) Oacc[j] = 0.f;

    const float16v ZF = (float16v)(0.0f);   // literal zero C — foldable to inline 0

    // staging mapping: 512 threads stage 256 keys x 16 d (2 chunks/thread).
    // sal preserves the slot->key bit-swap of the 256-thread version; sah picks
    // which pair of 64-key chunks this thread covers.
    int sd = tid & 15, sa = tid >> 4;          // sa in [0,32)
    int sal = sa & 15, sah = sa >> 4;          // sah in {0,1}
    int kb = ((sal & 1) << 3) | (((sal >> 1) & 1) << 2) | ((sal >> 2) << 4);

    short4v vpack[2];
    #pragma unroll
    for (int c2 = 0; c2 < 2; ++c2) {
        int cc = sah * 2 + c2;
        const short* vp = Vh + (size_t)(cc * 64 + kb) * 16 + sd;
        vpack[c2].x = vp[0]; vpack[c2].y = vp[16];
        vpack[c2].z = vp[32]; vpack[c2].w = vp[48];
    }

    short8 kf1 = *(const short8*)(Kh + (size_t)m * 16 + hi * 8);
    short8 kf2 = *(const short8*)(Kh + (size_t)(32 + m) * 16 + hi * 8);

    for (int sc = 0; sc < N; sc += 256) {
        __syncthreads();
        #pragma unroll
        for (int c2 = 0; c2 < 2; ++c2) {
            int cc = sah * 2 + c2;
            *(short4v*)(&Vt[sd][cc * 64 + sal * 4]) = vpack[c2];
        }
        if (sc + 256 < N) {   // V prefetch for next chunk — in flight across barrier
            #pragma unroll
            for (int c2 = 0; c2 < 2; ++c2) {
                int cc = sah * 2 + c2;
                const short* vp = Vh + (size_t)(sc + 256 + cc * 64 + kb) * 16 + sd;
                vpack[c2].x = vp[0]; vpack[c2].y = vp[16];
                vpack[c2].z = vp[32]; vpack[c2].w = vp[48];
            }
        }
        __syncthreads();

        #pragma unroll
        for (int it = 0; it < 4; ++it) {
            int c = sc + it * 64;
            int cn = (c + 64) & (N - 1);

            union { uint4v u; short8 s; } pk;
            short8 vf;

            // ---- first 32 keys: S = kf1 * qf ----
            float16v S = __builtin_amdgcn_mfma_f32_32x32x16_bf16(kf1, qf, ZF, 0, 0, 0);
            kf1 = *(const short8*)(Kh + (size_t)(cn + m) * 16 + hi * 8);

            pk.u = (uint4v){
                cvt_pk2(__builtin_amdgcn_exp2f(S[0]), __builtin_amdgcn_exp2f(S[1])),
                cvt_pk2(__builtin_amdgcn_exp2f(S[2]), __builtin_amdgcn_exp2f(S[3])),
                cvt_pk2(__builtin_amdgcn_exp2f(S[4]), __builtin_amdgcn_exp2f(S[5])),
                cvt_pk2(__builtin_amdgcn_exp2f(S[6]), __builtin_amdgcn_exp2f(S[7]))};
            vf = *(short8*)(&Vt[m][it * 64 + 0 * 16 + hi * 8]);
            Oacc = __builtin_amdgcn_mfma_f32_32x32x16_bf16(vf, pk.s, Oacc, 0, 0, 0);

            pk.u = (uint4v){
                cvt_pk2(__builtin_amdgcn_exp2f(S[8]),  __builtin_amdgcn_exp2f(S[9])),
                cvt_pk2(__builtin_amdgcn_exp2f(S[10]), __builtin_amdgcn_exp2f(S[11])),
                cvt_pk2(__builtin_amdgcn_exp2f(S[12]), __builtin_amdgcn_exp2f(S[13])),
                cvt_pk2(__builtin_amdgcn_exp2f(S[14]), __builtin_amdgcn_exp2f(S[15]))};
            vf = *(short8*)(&Vt[m][it * 64 + 1 * 16 + hi * 8]);
            Oacc = __builtin_amdgcn_mfma_f32_32x32x16_bf16(vf, pk.s, Oacc, 0, 0, 0);

            // ---- second 32 keys: S reused (peak S-liveness stays 16) ----
            S = __builtin_amdgcn_mfma_f32_32x32x16_bf16(kf2, qf, ZF, 0, 0, 0);
            kf2 = *(const short8*)(Kh + (size_t)(cn + 32 + m) * 16 + hi * 8);

            pk.u = (uint4v){
                cvt_pk2(__builtin_amdgcn_exp2f(S[0]), __builtin_amdgcn_exp2f(S[1])),
                cvt_pk2(__builtin_amdgcn_exp2f(S[2]), __builtin_amdgcn_exp2f(S[3])),
                cvt_pk2(__builtin_amdgcn_exp2f(S[4]), __builtin_amdgcn_exp2f(S[5])),
                cvt_pk2(__builtin_amdgcn_exp2f(S[6]), __builtin_amdgcn_exp2f(S[7]))};
            vf = *(short8*)(&Vt[m][it * 64 + 2 * 16 + hi * 8]);
            Oacc = __builtin_amdgcn_mfma_f32_32x32x16_bf16(vf, pk.s, Oacc, 0, 0, 0);

            pk.u = (uint4v){
                cvt_pk2(__builtin_amdgcn_exp2f(S[8]),  __builtin_amdgcn_exp2f(S[9])),
                cvt_pk2(__builtin_amdgcn_exp2f(S[10]), __builtin_amdgcn_exp2f(S[11])),
                cvt_pk2(__builtin_amdgcn_exp2f(S[12]), __builtin_amdgcn_exp2f(S[13])),
                cvt_pk2(__builtin_amdgcn_exp2f(S[14]), __builtin_amdgcn_exp2f(S[15]))};
            vf = *(short8*)(&Vt[m][it * 64 + 3 * 16 + hi * 8]);
            Oacc = __builtin_amdgcn_mfma_f32_32x32x16_bf16(vf, pk.s, Oacc, 0, 0, 0);
        }
    }

    float Lq = __shfl(Oacc[8], m, 64);
    float inv = 1.0f / Lq;
    uint32_t o0 = cvt_pk2(Oacc[0] * inv, Oacc[1] * inv);
    uint32_t o1 = cvt_pk2(Oacc[2] * inv, Oacc[3] * inv);
    uint32_t o2 = cvt_pk2(Oacc[4] * inv, Oacc[5] * inv);
    uint32_t o3 = cvt_pk2(Oacc[6] * inv, Oacc[7] * inv);
    short* row = Out + ((size_t)(b * 2048 + qbase + m)) * 256 + h * 16;
    uint2 w0; w0.x = o0; w0.y = o1;
    uint2 w1; w1.x = o2; w1.y = o3;
    *(uint2*)(row + hi * 4) = w0;
    *(uint2*)(row + 8 + hi * 4) = w1;
}

// ---------------- launcher ----------------

extern "C" void kernel_launch(void* const* d_in, const int* in_sizes, int n_in,
                              void* d_out, int out_size, void* d_ws, size_t ws_size,
                              hipStream_t stream) {
    const float* x      = (const float*)d_in[0];
    const float* w_qkv  = (const float*)d_in[1];
    const float* b_qkv  = (const float*)d_in[2];
    const float* w_proj = (const float*)d_in[3];
    const float* b_proj = (const float*)d_in[4];
    float* out = (float*)d_out;

    short* wqkvT  = (short*)d_ws;          // 768*256
    short* wprojT = wqkvT + 196608;        // 256*256
    short* Qb     = wprojT + 65536;        // (B*H, N, D) bf16
    short* Kb     = Qb + 2097152;
    short* Vb     = Kb + 2097152;
    short* Ab     = Vb + 2097152;          // attention output (B,N,C) bf16

    cvtW_kernel<<<64, 256, 0, stream>>>(w_qkv, w_proj, wqkvT, wprojT);

    gemm_kernel<0><<<dim3(128, 12), 256, 0, stream>>>(x, wqkvT, b_qkv, Qb, Kb, Vb, nullptr);

    attn_kernel<<<dim3(8, 64), 512, 0, stream>>>(Qb, Kb, Vb, Ab);

    gemm_kernel<1><<<dim3(128, 4), 256, 0, stream>>>(Ab, wprojT, b_proj,
                                                     nullptr, nullptr, nullptr, out);
}